// Round 12
// baseline (203.145 us; speedup 1.0000x reference)
//
#include <hip/hip_runtime.h>
#include <stdint.h>

#define NB 8
#define SS 2048
#define DD 256
#define NEGV -1e9f
#define LDSW 136

typedef __attribute__((ext_vector_type(8))) __bf16 bf16x8;
typedef __attribute__((ext_vector_type(4))) float f32x4;

union U16 { uint4 u; bf16x8 b; unsigned short us[8]; };

__device__ __forceinline__ unsigned short tobf(float v) {
  union { float f; uint32_t u; } c; c.f = v;
  uint32_t r = (c.u + 0x7fffu + ((c.u >> 16) & 1u)) >> 16;
  return (unsigned short)r;
}
__device__ __forceinline__ float frombf(unsigned short v) {
  union { uint32_t u; float f; } c; c.u = ((uint32_t)v) << 16;
  return c.f;
}

__device__ __forceinline__ void glds16(const unsigned short* g, unsigned short* l) {
  __builtin_amdgcn_global_load_lds(
      (const __attribute__((address_space(1))) uint32_t*)g,
      (__attribute__((address_space(3))) uint32_t*)l, 16, 0, 0);
}

__device__ __forceinline__ void stage_tile(const unsigned short* src, int ld,
                                           unsigned short* lbuf, int w, int lane) {
  int rl = lane >> 2;
  int cs = (lane & 3) * 8;
  glds16(src + (size_t)(w * 32 + rl) * ld + cs, lbuf + w * 1024);
  glds16(src + (size_t)(w * 32 + 16 + rl) * ld + cs, lbuf + w * 1024 + 512);
}

// 128x128 tile GEMM core (R6-proven): 256 thr / 4 waves, dbuf LDS 32KB.
template <int NSTEPS>
__device__ __forceinline__ void gemm128_tile(
    const unsigned short* __restrict__ A, int lda,
    const unsigned short* __restrict__ Bt, int ldb,
    unsigned short* smem, f32x4 (&acc)[4][4]) {
  unsigned short* lA = smem;
  unsigned short* lB = smem + 8192;
  const int w = threadIdx.x >> 6, lane = threadIdx.x & 63;
  const int lr = lane & 15, lg = lane >> 4;
  const int wm = w >> 1, wn = w & 1;
#pragma unroll
  for (int i = 0; i < 4; ++i)
#pragma unroll
    for (int j = 0; j < 4; ++j) acc[i][j] = (f32x4){0.f, 0.f, 0.f, 0.f};
  stage_tile(A, lda, lA, w, lane);
  stage_tile(Bt, ldb, lB, w, lane);
  __syncthreads();
  for (int s = 0; s < NSTEPS; ++s) {
    const unsigned short* cA = lA + (s & 1) * 4096;
    const unsigned short* cB = lB + (s & 1) * 4096;
    if (s + 1 < NSTEPS) {
      stage_tile(A + (s + 1) * 32, lda, lA + ((s + 1) & 1) * 4096, w, lane);
      stage_tile(Bt + (s + 1) * 32, ldb, lB + ((s + 1) & 1) * 4096, w, lane);
    }
    bf16x8 am[4], bn[4];
#pragma unroll
    for (int i = 0; i < 4; ++i) {
      U16 u; u.u = *(const uint4*)(cA + (wm * 64 + i * 16 + lr) * 32 + lg * 8);
      am[i] = u.b;
      U16 v; v.u = *(const uint4*)(cB + (wn * 64 + i * 16 + lr) * 32 + lg * 8);
      bn[i] = v.b;
    }
#pragma unroll
    for (int i = 0; i < 4; ++i)
#pragma unroll
      for (int j = 0; j < 4; ++j)
        acc[i][j] = __builtin_amdgcn_mfma_f32_16x16x32_bf16(am[i], bn[j], acc[i][j], 0, 0, 0);
    __syncthreads();
  }
}

// 128x256 tile GEMM core: 512 thr / 8 waves (2m x 4n), dbuf LDS 48KB.
template <int NSTEPS>
__device__ __forceinline__ void gemm256_acc(
    const unsigned short* __restrict__ A, int lda,
    const unsigned short* __restrict__ Bt, int ldb,
    unsigned short* smem, f32x4 (&acc)[4][4]) {
  unsigned short* lA = smem;
  unsigned short* lB = smem + 8192;
  const int tid = threadIdx.x;
  const int w = tid >> 6, lane = tid & 63;
  const int lr = lane & 15, lg = lane >> 4;
  const int wm = w >> 2, wn = w & 3;
  const int rl = lane >> 2, cs = (lane & 3) * 8;
#pragma unroll
  for (int i = 0; i < 4; ++i)
#pragma unroll
    for (int j = 0; j < 4; ++j) acc[i][j] = (f32x4){0.f, 0.f, 0.f, 0.f};
  glds16(A + (size_t)(w * 16 + rl) * lda + cs, lA + w * 512);
  glds16(Bt + (size_t)(w * 32 + rl) * ldb + cs, lB + w * 1024);
  glds16(Bt + (size_t)(w * 32 + 16 + rl) * ldb + cs, lB + w * 1024 + 512);
  __syncthreads();
  for (int s = 0; s < NSTEPS; ++s) {
    const unsigned short* cA = lA + (s & 1) * 4096;
    const unsigned short* cB = lB + (s & 1) * 8192;
    if (s + 1 < NSTEPS) {
      const unsigned short* An = A + (s + 1) * 32;
      const unsigned short* Bn = Bt + (s + 1) * 32;
      glds16(An + (size_t)(w * 16 + rl) * lda + cs, lA + ((s + 1) & 1) * 4096 + w * 512);
      glds16(Bn + (size_t)(w * 32 + rl) * ldb + cs, lB + ((s + 1) & 1) * 8192 + w * 1024);
      glds16(Bn + (size_t)(w * 32 + 16 + rl) * ldb + cs,
             lB + ((s + 1) & 1) * 8192 + w * 1024 + 512);
    }
    bf16x8 am[4], bn[4];
#pragma unroll
    for (int i = 0; i < 4; ++i) {
      U16 u; u.u = *(const uint4*)(cA + (wm * 64 + i * 16 + lr) * 32 + lg * 8);
      am[i] = u.b;
      U16 v; v.u = *(const uint4*)(cB + (wn * 64 + i * 16 + lr) * 32 + lg * 8);
      bn[i] = v.b;
    }
#pragma unroll
    for (int i = 0; i < 4; ++i)
#pragma unroll
      for (int j = 0; j < 4; ++j)
        acc[i][j] = __builtin_amdgcn_mfma_f32_16x16x32_bf16(am[i], bn[j], acc[i][j], 0, 0, 0);
    __syncthreads();
  }
}

// ------- LN1 + weight-convert merged launch (independent start work) --------
__global__ __launch_bounds__(256) void lnw_kernel(
    const float* __restrict__ in, const float* __restrict__ w,
    const float* __restrict__ bparm, unsigned short* __restrict__ outb,
    const float* __restrict__ w1, unsigned short* __restrict__ w1bT,
    const float* __restrict__ w2, unsigned short* __restrict__ w2bT) {
  __shared__ unsigned short tile[64][72];
  int bid = blockIdx.x;
  if (bid < 4096) {
    int row = bid * 4 + (threadIdx.x >> 6);
    int lane = threadIdx.x & 63;
    const float* xr = in + (size_t)row * DD;
    float4 v = *(const float4*)(xr + lane * 4);
    float s = v.x + v.y + v.z + v.w;
    float s2 = v.x * v.x + v.y * v.y + v.z * v.z + v.w * v.w;
#pragma unroll
    for (int m = 1; m < 64; m <<= 1) { s += __shfl_xor(s, m); s2 += __shfl_xor(s2, m); }
    float mu = s * (1.f / DD);
    float var = s2 * (1.f / DD) - mu * mu;
    float rs = rsqrtf(var + 1e-5f);
    float4 wv = *(const float4*)(w + lane * 4);
    float4 bv = *(const float4*)(bparm + lane * 4);
    ushort4 o;
    o.x = tobf((v.x - mu) * rs * wv.x + bv.x);
    o.y = tobf((v.y - mu) * rs * wv.y + bv.y);
    o.z = tobf((v.z - mu) * rs * wv.z + bv.z);
    o.w = tobf((v.w - mu) * rs * wv.w + bv.w);
    *(ushort4*)(outb + (size_t)row * DD + lane * 4) = o;
  } else {
    int t = bid - 4096;
    const float* src; unsigned short* dst; int K, N;
    if (t < 64) { src = w1; dst = w1bT; K = 256; N = 1024; }
    else        { src = w2; dst = w2bT; K = 1024; N = 256; t -= 64; }
    int nt = N >> 6;
    int kt = t / nt, ntb = t % nt;
    int k0 = kt * 64, n0 = ntb * 64;
    int tt = threadIdx.x;
    int r = tt >> 2, c4 = (tt & 3) * 16;
    const float* s = src + (size_t)(k0 + r) * N + n0 + c4;
#pragma unroll
    for (int j = 0; j < 16; ++j) tile[r][c4 + j] = tobf(s[j]);
    __syncthreads();
    union { unsigned short us[16]; uint4 u[2]; } tmp;
    int nr = tt >> 2, ks = (tt & 3) * 16;
#pragma unroll
    for (int j = 0; j < 16; ++j) tmp.us[j] = tile[ks + j][nr];
    unsigned short* d = dst + (size_t)(n0 + nr) * K + k0 + ks;
    *(uint4*)d = tmp.u[0];
    *(uint4*)(d + 8) = tmp.u[1];
  }
}

// --- mega-fused: transpose (1024) | symmetric qk (1088) | rm-softmax (4096) -
// All branches depend only on hb (and inputs); fully independent -> overlap.
__global__ __launch_bounds__(256) void fused_kernel(
    const unsigned short* __restrict__ hb,
    unsigned short* __restrict__ hbT,
    unsigned short* __restrict__ S,
    const float* __restrict__ r_mat,
    const float* __restrict__ attn,
    const float* __restrict__ pad,
    unsigned short* __restrict__ rmsm) {
  __shared__ unsigned short smem[17408];
  int bid = blockIdx.x;
  if (bid < 1024) {
    // ---- transpose hb -> hbT, 64x64 tiles ----
    unsigned short (*tile)[72] = (unsigned short (*)[72])smem;
    int b = bid >> 7;
    int rest = bid & 127;
    int st = rest >> 2, dt = rest & 3;
    int s0 = st * 64, d0 = dt * 64;
    int t = threadIdx.x;
    int r = t >> 2, cs = (t & 3) * 16;
    const unsigned short* src = hb + ((size_t)b * SS + s0 + r) * DD + d0 + cs;
    *(uint4*)&tile[r][cs] = *(const uint4*)src;
    *(uint4*)&tile[r][cs + 8] = *(const uint4*)(src + 8);
    __syncthreads();
    union { unsigned short us[16]; uint4 u[2]; } tmp;
    int dr = t >> 2, sseg = (t & 3) * 16;
#pragma unroll
    for (int j = 0; j < 16; ++j) tmp.us[j] = tile[sseg + j][dr];
    unsigned short* dst = hbT + ((size_t)b * DD + d0 + dr) * SS + s0 + sseg;
    *(uint4*)dst = tmp.u[0];
    *(uint4*)(dst + 8) = tmp.u[1];
  } else if (bid < 2112) {
    // ---- symmetric QK^T (triangular), primary direct + mirror bounce ----
    int t = bid - 1024;
    int b = t & 7;
    int tri = t >> 3;
    int mb = 0, rem = tri;
    while (rem >= 16 - mb) { rem -= 16 - mb; ++mb; }
    int nb = mb + rem;
    const unsigned short* A = hb + (size_t)(b * SS + mb * 128) * DD;
    const unsigned short* Bt = hb + (size_t)(b * SS + nb * 128) * DD;
    f32x4 acc[4][4];
    gemm128_tile<8>(A, DD, Bt, DD, smem, acc);
    int tid = threadIdx.x;
    int w = tid >> 6, lane = tid & 63;
    int lr = lane & 15, lg = lane >> 4;
    int wm = w >> 1, wn = w & 1;
    unsigned short* Sb = S + (size_t)b * SS * SS;
#pragma unroll
    for (int i = 0; i < 4; ++i)
#pragma unroll
      for (int j = 0; j < 4; ++j)
#pragma unroll
        for (int r = 0; r < 4; ++r) {
          int m = mb * 128 + wm * 64 + i * 16 + lg * 4 + r;
          int n = nb * 128 + wn * 64 + j * 16 + lr;
          Sb[(size_t)m * SS + n] = tobf(acc[i][j][r] * 0.0625f);
        }
    if (mb != nb) {
#pragma unroll
      for (int i = 0; i < 4; ++i)
#pragma unroll
        for (int j = 0; j < 4; ++j) {
          int col = wn * 64 + j * 16 + lr;
#pragma unroll
          for (int r = 0; r < 4; ++r) {
            int row = wm * 64 + i * 16 + lg * 4 + r;
            smem[col * LDSW + row] = tobf(acc[i][j][r] * 0.0625f);
          }
        }
      __syncthreads();
      int row2 = tid >> 1, half = (tid & 1) * 64;
      const unsigned short* s = smem + row2 * LDSW + half;
      unsigned short* d = Sb + (size_t)(nb * 128 + row2) * SS + mb * 128 + half;
      uint4 vv[8];
#pragma unroll
      for (int k = 0; k < 8; ++k) vv[k] = *(const uint4*)(s + k * 8);
#pragma unroll
      for (int k = 0; k < 8; ++k) *(uint4*)(d + k * 8) = vv[k];
    }
  } else {
    // ---- rm pass: rmsm = bf16(softmax(mask(r_mat))), one wave per row ----
    int row = (bid - 2112) * 4 + (threadIdx.x >> 6);
    int lane = threadIdx.x & 63;
    int b = row >> 11, q = row & 2047;
    const float* rrow = r_mat + (size_t)row * SS;
    const float* arow = attn + (size_t)q * SS;
    const float* prow = pad + (size_t)b * SS;
    float rm[32];
    float mx = -__builtin_inff();
#pragma unroll
    for (int i = 0; i < 8; ++i) {
      int c = i * 256 + lane * 4;
      float4 rv = *(const float4*)(rrow + c);
      float4 av = *(const float4*)(arow + c);
      float4 pv = *(const float4*)(prow + c);
      float v0 = (pv.x == 0.f || av.x == 0.f) ? NEGV : rv.x;
      float v1 = (pv.y == 0.f || av.y == 0.f) ? NEGV : rv.y;
      float v2 = (pv.z == 0.f || av.z == 0.f) ? NEGV : rv.z;
      float v3 = (pv.w == 0.f || av.w == 0.f) ? NEGV : rv.w;
      rm[i * 4 + 0] = v0; rm[i * 4 + 1] = v1; rm[i * 4 + 2] = v2; rm[i * 4 + 3] = v3;
      mx = fmaxf(mx, fmaxf(fmaxf(v0, v1), fmaxf(v2, v3)));
    }
#pragma unroll
    for (int m = 1; m < 64; m <<= 1) mx = fmaxf(mx, __shfl_xor(mx, m));
    float sum = 0.f;
#pragma unroll
    for (int j = 0; j < 32; ++j) { rm[j] = __expf(rm[j] - mx); sum += rm[j]; }
#pragma unroll
    for (int m = 1; m < 64; m <<= 1) sum += __shfl_xor(sum, m);
    float inv = 1.f / sum;
    unsigned short* orow = rmsm + (size_t)row * SS;
#pragma unroll
    for (int i = 0; i < 8; ++i) {
      int c = i * 256 + lane * 4;
      ushort4 o;
      o.x = tobf(rm[i * 4 + 0] * inv);
      o.y = tobf(rm[i * 4 + 1] * inv);
      o.z = tobf(rm[i * 4 + 2] * inv);
      o.w = tobf(rm[i * 4 + 3] * inv);
      *(ushort4*)(orow + c) = o;
    }
  }
}

// ------------- smfuse2: P = softmax(S + rmsm), in place over S --------------
__global__ __launch_bounds__(256) void smfuse2_kernel(
    const unsigned short* __restrict__ rmsm,
    unsigned short* __restrict__ S) {
  int row = blockIdx.x * 4 + (threadIdx.x >> 6);
  int lane = threadIdx.x & 63;
  unsigned short* srow = S + (size_t)row * SS;
  const unsigned short* mrow = rmsm + (size_t)row * SS;
  float sc[32];
  float mx2 = -__builtin_inff();
#pragma unroll
  for (int i = 0; i < 8; ++i) {
    int c = i * 256 + lane * 4;
    ushort4 sv = *(const ushort4*)(srow + c);
    ushort4 mv = *(const ushort4*)(mrow + c);
    float s0 = frombf(sv.x) + frombf(mv.x);
    float s1 = frombf(sv.y) + frombf(mv.y);
    float s2 = frombf(sv.z) + frombf(mv.z);
    float s3 = frombf(sv.w) + frombf(mv.w);
    sc[i * 4 + 0] = s0; sc[i * 4 + 1] = s1; sc[i * 4 + 2] = s2; sc[i * 4 + 3] = s3;
    mx2 = fmaxf(mx2, fmaxf(fmaxf(s0, s1), fmaxf(s2, s3)));
  }
#pragma unroll
  for (int m = 1; m < 64; m <<= 1) mx2 = fmaxf(mx2, __shfl_xor(mx2, m));
  float sum2 = 0.f;
#pragma unroll
  for (int j = 0; j < 32; ++j) { sc[j] = __expf(sc[j] - mx2); sum2 += sc[j]; }
#pragma unroll
  for (int m = 1; m < 64; m <<= 1) sum2 += __shfl_xor(sum2, m);
  float inv2 = 1.f / sum2;
#pragma unroll
  for (int i = 0; i < 8; ++i) {
    int c = i * 256 + lane * 4;
    ushort4 o;
    o.x = tobf(sc[i * 4 + 0] * inv2);
    o.y = tobf(sc[i * 4 + 1] * inv2);
    o.z = tobf(sc[i * 4 + 2] * inv2);
    o.w = tobf(sc[i * 4 + 3] * inv2);
    *(ushort4*)(srow + c) = o;
  }
}

// ---- PV split-K x4, BN=256 8-wave core, direct stores (R10) ----------------
__global__ __launch_bounds__(512) void pv_kernel(
    const unsigned short* __restrict__ P,
    const unsigned short* __restrict__ hbT,
    unsigned short* __restrict__ pvp) {
  __shared__ unsigned short smem[24576];
  int bid = blockIdx.x;
  int b = bid & 7;
  int rest = bid >> 3;
  int ks = rest & 3, mb = rest >> 2;
  const unsigned short* A = P + (size_t)(b * SS + mb * 128) * SS + ks * 512;
  const unsigned short* Bt = hbT + (size_t)(b * DD) * SS + ks * 512;
  f32x4 acc[4][4];
  gemm256_acc<16>(A, SS, Bt, SS, smem, acc);
  int w = threadIdx.x >> 6, lane = threadIdx.x & 63;
  int lr = lane & 15, lg = lane >> 4;
  int wm = w >> 2, wn = w & 3;
  unsigned short* O = pvp + ((size_t)(ks << 14) + (b << 11) + mb * 128) * DD;
#pragma unroll
  for (int i = 0; i < 4; ++i)
#pragma unroll
    for (int j = 0; j < 4; ++j)
#pragma unroll
      for (int r = 0; r < 4; ++r) {
        int m = wm * 64 + i * 16 + lg * 4 + r;
        int n = wn * 64 + j * 16 + lr;
        O[(size_t)m * DD + n] = tobf(acc[i][j][r]);
      }
}

// ---------------- pv reduce + residual + fused LN2 --------------------------
__global__ __launch_bounds__(256) void pvreduce_kernel(
    const unsigned short* __restrict__ pvp,
    const float* __restrict__ x,
    const float* __restrict__ ln2w,
    const float* __restrict__ ln2b,
    float* __restrict__ out,
    unsigned short* __restrict__ h2b) {
  int r = blockIdx.x * 4 + (threadIdx.x >> 6);
  int lane = threadIdx.x & 63;
  int c = lane * 4;
  float o[4] = {0.f, 0.f, 0.f, 0.f};
#pragma unroll
  for (int ks = 0; ks < 4; ++ks) {
    ushort4 pk = *(const ushort4*)(pvp + ((size_t)(ks << 14) + r) * DD + c);
    o[0] += frombf(pk.x); o[1] += frombf(pk.y);
    o[2] += frombf(pk.z); o[3] += frombf(pk.w);
  }
  float4 xv = *(const float4*)(x + (size_t)r * DD + c);
  float val[4] = {o[0] + xv.x, o[1] + xv.y, o[2] + xv.z, o[3] + xv.w};
  float4 ov = {val[0], val[1], val[2], val[3]};
  *(float4*)(out + (size_t)r * DD + c) = ov;
  float s = val[0] + val[1] + val[2] + val[3];
  float s2 = val[0] * val[0] + val[1] * val[1] + val[2] * val[2] + val[3] * val[3];
#pragma unroll
  for (int m = 1; m < 64; m <<= 1) { s += __shfl_xor(s, m); s2 += __shfl_xor(s2, m); }
  float mu = s * (1.f / DD);
  float var = s2 * (1.f / DD) - mu * mu;
  float rsv = rsqrtf(var + 1e-5f);
  float4 wv = *(const float4*)(ln2w + c);
  float4 bv = *(const float4*)(ln2b + c);
  ushort4 h;
  h.x = tobf((val[0] - mu) * rsv * wv.x + bv.x);
  h.y = tobf((val[1] - mu) * rsv * wv.y + bv.y);
  h.z = tobf((val[2] - mu) * rsv * wv.z + bv.z);
  h.w = tobf((val[3] - mu) * rsv * wv.w + bv.w);
  *(ushort4*)(h2b + (size_t)r * DD + c) = h;
}

// ---- FFN1: relu(h2b @ w1 + b1), BN=256 8-wave core, direct stores ----------
__global__ __launch_bounds__(512) void ffn1_kernel(
    const unsigned short* __restrict__ A0,
    const unsigned short* __restrict__ Bt0,
    const float* __restrict__ bias,
    unsigned short* __restrict__ Out) {
  __shared__ unsigned short smem[24576];
  int bid = blockIdx.x;
  int nb = bid & 3, mb = bid >> 2;
  const unsigned short* A = A0 + (size_t)(mb * 128) * 256;
  const unsigned short* Bt = Bt0 + (size_t)(nb * 256) * 256;
  f32x4 acc[4][4];
  gemm256_acc<8>(A, 256, Bt, 256, smem, acc);
  int w = threadIdx.x >> 6, lane = threadIdx.x & 63;
  int lr = lane & 15, lg = lane >> 4;
  int wm = w >> 2, wn = w & 3;
#pragma unroll
  for (int i = 0; i < 4; ++i)
#pragma unroll
    for (int j = 0; j < 4; ++j)
#pragma unroll
      for (int r = 0; r < 4; ++r) {
        int m = mb * 128 + wm * 64 + i * 16 + lg * 4 + r;
        int n = nb * 256 + wn * 64 + j * 16 + lr;
        float v = fmaxf(acc[i][j][r] + bias[n], 0.f);
        Out[(size_t)m * 1024 + n] = tobf(v);
      }
}

// ---- FFN2 split-K x4, BN=256 8-wave core, direct stores --------------------
__global__ __launch_bounds__(512) void ffn2_kernel(
    const unsigned short* __restrict__ A0,
    const unsigned short* __restrict__ Bt0,
    unsigned short* __restrict__ f2p) {
  __shared__ unsigned short smem[24576];
  int bid = blockIdx.x;
  int ks = bid & 3, mb = bid >> 2;
  const unsigned short* A = A0 + (size_t)(mb * 128) * 1024 + ks * 256;
  const unsigned short* Bt = Bt0 + ks * 256;
  f32x4 acc[4][4];
  gemm256_acc<8>(A, 1024, Bt, 1024, smem, acc);
  int w = threadIdx.x >> 6, lane = threadIdx.x & 63;
  int lr = lane & 15, lg = lane >> 4;
  int wm = w >> 2, wn = w & 3;
  unsigned short* O = f2p + ((size_t)(ks << 14) + mb * 128) * DD;
#pragma unroll
  for (int i = 0; i < 4; ++i)
#pragma unroll
    for (int j = 0; j < 4; ++j)
#pragma unroll
      for (int r = 0; r < 4; ++r) {
        int m = wm * 64 + i * 16 + lg * 4 + r;
        int n = wn * 64 + j * 16 + lr;
        O[(size_t)m * DD + n] = tobf(acc[i][j][r]);
      }
}

// ---------------- ffn2 reduce + bias + residual (out += ffn) ----------------
__global__ __launch_bounds__(256) void f2reduce_kernel(
    const unsigned short* __restrict__ f2p,
    const float* __restrict__ bias,
    float* __restrict__ out) {
  int r = blockIdx.x * 4 + (threadIdx.x >> 6);
  int lane = threadIdx.x & 63;
  int c = lane * 4;
  float o[4] = {0.f, 0.f, 0.f, 0.f};
#pragma unroll
  for (int ks = 0; ks < 4; ++ks) {
    ushort4 pk = *(const ushort4*)(f2p + ((size_t)(ks << 14) + r) * DD + c);
    o[0] += frombf(pk.x); o[1] += frombf(pk.y);
    o[2] += frombf(pk.z); o[3] += frombf(pk.w);
  }
  float4 bv = *(const float4*)(bias + c);
  float* orow = out + (size_t)r * DD + c;
  float4 cur = *(const float4*)orow;
  float4 res = {cur.x + o[0] + bv.x, cur.y + o[1] + bv.y,
                cur.z + o[2] + bv.z, cur.w + o[3] + bv.w};
  *(float4*)orow = res;
}

extern "C" void kernel_launch(void* const* d_in, const int* in_sizes, int n_in,
                              void* d_out, int out_size, void* d_ws, size_t ws_size,
                              hipStream_t stream) {
  const float* x     = (const float*)d_in[0];
  const float* r_mat = (const float*)d_in[1];
  const float* attn  = (const float*)d_in[2];
  const float* pad   = (const float*)d_in[3];
  const float* ln1w  = (const float*)d_in[4];
  const float* ln1b  = (const float*)d_in[5];
  const float* ln2w  = (const float*)d_in[6];
  const float* ln2b  = (const float*)d_in[7];
  const float* w1    = (const float*)d_in[8];
  const float* b1    = (const float*)d_in[9];
  const float* w2    = (const float*)d_in[10];
  const float* b2    = (const float*)d_in[11];
  float* out = (float*)d_out;

  uint8_t* ws = (uint8_t*)d_ws;
  unsigned short* hb   = (unsigned short*)(ws + 0);           // 8 MB
  unsigned short* hbT  = (unsigned short*)(ws + 8388608);     // 8 MB
  unsigned short* h2b  = (unsigned short*)(ws + 16777216);    // 8 MB
  unsigned short* w1bT = (unsigned short*)(ws + 25165824);    // 0.5 MB
  unsigned short* w2bT = (unsigned short*)(ws + 25690112);    // 0.5 MB
  unsigned short* S    = (unsigned short*)(ws + 33554432);    // 67 MB bf16 [B,S,S]
  unsigned short* pvp  = (unsigned short*)(ws + 100663296);   // 33.5 MB bf16 [4][B*S][D]
  unsigned short* rmsm = (unsigned short*)(ws + 134217728);   // 67 MB bf16 [B,S,S]
  unsigned short* t    = S;                                   // ffn1 out aliases S
  unsigned short* f2p  = pvp;                                 // ffn2 partials alias pvp

  hipLaunchKernelGGL(lnw_kernel, dim3(4224), dim3(256), 0, stream,
                     x, ln1w, ln1b, hb, w1, w1bT, w2, w2bT);
  hipLaunchKernelGGL(fused_kernel, dim3(6208), dim3(256), 0, stream,
                     hb, hbT, S, r_mat, attn, pad, rmsm);
  hipLaunchKernelGGL(smfuse2_kernel, dim3(4096), dim3(256), 0, stream, rmsm, S);
  hipLaunchKernelGGL(pv_kernel, dim3(512), dim3(512), 0, stream, S, hbT, pvp);
  hipLaunchKernelGGL(pvreduce_kernel, dim3(4096), dim3(256), 0, stream,
                     pvp, x, ln2w, ln2b, out, h2b);
  hipLaunchKernelGGL(ffn1_kernel, dim3(512), dim3(512), 0, stream, h2b, w1bT, b1, t);
  hipLaunchKernelGGL(ffn2_kernel, dim3(512), dim3(512), 0, stream, t, w2bT, f2p);
  hipLaunchKernelGGL(f2reduce_kernel, dim3(4096), dim3(256), 0, stream, f2p, b2, out);
}

// Round 13
// 184.632 us; speedup vs baseline: 1.1003x; 1.1003x over previous
//
#include <hip/hip_runtime.h>
#include <stdint.h>

#define NB 8
#define SS 2048
#define DD 256
#define NEGV -1e9f
#define LDSW 136

typedef __attribute__((ext_vector_type(8))) __bf16 bf16x8;
typedef __attribute__((ext_vector_type(4))) float f32x4;

union U16 { uint4 u; bf16x8 b; unsigned short us[8]; };

__device__ __forceinline__ unsigned short tobf(float v) {
  union { float f; uint32_t u; } c; c.f = v;
  uint32_t r = (c.u + 0x7fffu + ((c.u >> 16) & 1u)) >> 16;
  return (unsigned short)r;
}
__device__ __forceinline__ float frombf(unsigned short v) {
  union { uint32_t u; float f; } c; c.u = ((uint32_t)v) << 16;
  return c.f;
}

__device__ __forceinline__ void glds16(const unsigned short* g, unsigned short* l) {
  __builtin_amdgcn_global_load_lds(
      (const __attribute__((address_space(1))) uint32_t*)g,
      (__attribute__((address_space(3))) uint32_t*)l, 16, 0, 0);
}

__device__ __forceinline__ void stage_tile(const unsigned short* src, int ld,
                                           unsigned short* lbuf, int w, int lane) {
  int rl = lane >> 2;
  int cs = (lane & 3) * 8;
  glds16(src + (size_t)(w * 32 + rl) * ld + cs, lbuf + w * 1024);
  glds16(src + (size_t)(w * 32 + 16 + rl) * ld + cs, lbuf + w * 1024 + 512);
}

// 128x128 tile GEMM core (R6-proven): 256 thr / 4 waves, dbuf LDS 32KB.
template <int NSTEPS>
__device__ __forceinline__ void gemm128_tile(
    const unsigned short* __restrict__ A, int lda,
    const unsigned short* __restrict__ Bt, int ldb,
    unsigned short* smem, f32x4 (&acc)[4][4]) {
  unsigned short* lA = smem;
  unsigned short* lB = smem + 8192;
  const int w = threadIdx.x >> 6, lane = threadIdx.x & 63;
  const int lr = lane & 15, lg = lane >> 4;
  const int wm = w >> 1, wn = w & 1;
#pragma unroll
  for (int i = 0; i < 4; ++i)
#pragma unroll
    for (int j = 0; j < 4; ++j) acc[i][j] = (f32x4){0.f, 0.f, 0.f, 0.f};
  stage_tile(A, lda, lA, w, lane);
  stage_tile(Bt, ldb, lB, w, lane);
  __syncthreads();
  for (int s = 0; s < NSTEPS; ++s) {
    const unsigned short* cA = lA + (s & 1) * 4096;
    const unsigned short* cB = lB + (s & 1) * 4096;
    if (s + 1 < NSTEPS) {
      stage_tile(A + (s + 1) * 32, lda, lA + ((s + 1) & 1) * 4096, w, lane);
      stage_tile(Bt + (s + 1) * 32, ldb, lB + ((s + 1) & 1) * 4096, w, lane);
    }
    bf16x8 am[4], bn[4];
#pragma unroll
    for (int i = 0; i < 4; ++i) {
      U16 u; u.u = *(const uint4*)(cA + (wm * 64 + i * 16 + lr) * 32 + lg * 8);
      am[i] = u.b;
      U16 v; v.u = *(const uint4*)(cB + (wn * 64 + i * 16 + lr) * 32 + lg * 8);
      bn[i] = v.b;
    }
#pragma unroll
    for (int i = 0; i < 4; ++i)
#pragma unroll
      for (int j = 0; j < 4; ++j)
        acc[i][j] = __builtin_amdgcn_mfma_f32_16x16x32_bf16(am[i], bn[j], acc[i][j], 0, 0, 0);
    __syncthreads();
  }
}

// 128x256 tile GEMM core: 512 thr / 8 waves (2m x 4n), dbuf LDS 48KB.
template <int NSTEPS>
__device__ __forceinline__ void gemm256_acc(
    const unsigned short* __restrict__ A, int lda,
    const unsigned short* __restrict__ Bt, int ldb,
    unsigned short* smem, f32x4 (&acc)[4][4]) {
  unsigned short* lA = smem;
  unsigned short* lB = smem + 8192;
  const int tid = threadIdx.x;
  const int w = tid >> 6, lane = tid & 63;
  const int lr = lane & 15, lg = lane >> 4;
  const int wm = w >> 2, wn = w & 3;
  const int rl = lane >> 2, cs = (lane & 3) * 8;
#pragma unroll
  for (int i = 0; i < 4; ++i)
#pragma unroll
    for (int j = 0; j < 4; ++j) acc[i][j] = (f32x4){0.f, 0.f, 0.f, 0.f};
  glds16(A + (size_t)(w * 16 + rl) * lda + cs, lA + w * 512);
  glds16(Bt + (size_t)(w * 32 + rl) * ldb + cs, lB + w * 1024);
  glds16(Bt + (size_t)(w * 32 + 16 + rl) * ldb + cs, lB + w * 1024 + 512);
  __syncthreads();
  for (int s = 0; s < NSTEPS; ++s) {
    const unsigned short* cA = lA + (s & 1) * 4096;
    const unsigned short* cB = lB + (s & 1) * 8192;
    if (s + 1 < NSTEPS) {
      const unsigned short* An = A + (s + 1) * 32;
      const unsigned short* Bn = Bt + (s + 1) * 32;
      glds16(An + (size_t)(w * 16 + rl) * lda + cs, lA + ((s + 1) & 1) * 4096 + w * 512);
      glds16(Bn + (size_t)(w * 32 + rl) * ldb + cs, lB + ((s + 1) & 1) * 8192 + w * 1024);
      glds16(Bn + (size_t)(w * 32 + 16 + rl) * ldb + cs,
             lB + ((s + 1) & 1) * 8192 + w * 1024 + 512);
    }
    bf16x8 am[4], bn[4];
#pragma unroll
    for (int i = 0; i < 4; ++i) {
      U16 u; u.u = *(const uint4*)(cA + (wm * 64 + i * 16 + lr) * 32 + lg * 8);
      am[i] = u.b;
      U16 v; v.u = *(const uint4*)(cB + (wn * 64 + i * 16 + lr) * 32 + lg * 8);
      bn[i] = v.b;
    }
#pragma unroll
    for (int i = 0; i < 4; ++i)
#pragma unroll
      for (int j = 0; j < 4; ++j)
        acc[i][j] = __builtin_amdgcn_mfma_f32_16x16x32_bf16(am[i], bn[j], acc[i][j], 0, 0, 0);
    __syncthreads();
  }
}

// ------- LN1 + weight-convert merged launch (R11-proven) --------------------
__global__ __launch_bounds__(256) void lnw_kernel(
    const float* __restrict__ in, const float* __restrict__ w,
    const float* __restrict__ bparm, unsigned short* __restrict__ outb,
    const float* __restrict__ w1, unsigned short* __restrict__ w1bT,
    const float* __restrict__ w2, unsigned short* __restrict__ w2bT) {
  __shared__ unsigned short tile[64][72];
  int bid = blockIdx.x;
  if (bid < 4096) {
    int row = bid * 4 + (threadIdx.x >> 6);
    int lane = threadIdx.x & 63;
    const float* xr = in + (size_t)row * DD;
    float4 v = *(const float4*)(xr + lane * 4);
    float s = v.x + v.y + v.z + v.w;
    float s2 = v.x * v.x + v.y * v.y + v.z * v.z + v.w * v.w;
#pragma unroll
    for (int m = 1; m < 64; m <<= 1) { s += __shfl_xor(s, m); s2 += __shfl_xor(s2, m); }
    float mu = s * (1.f / DD);
    float var = s2 * (1.f / DD) - mu * mu;
    float rs = rsqrtf(var + 1e-5f);
    float4 wv = *(const float4*)(w + lane * 4);
    float4 bv = *(const float4*)(bparm + lane * 4);
    ushort4 o;
    o.x = tobf((v.x - mu) * rs * wv.x + bv.x);
    o.y = tobf((v.y - mu) * rs * wv.y + bv.y);
    o.z = tobf((v.z - mu) * rs * wv.z + bv.z);
    o.w = tobf((v.w - mu) * rs * wv.w + bv.w);
    *(ushort4*)(outb + (size_t)row * DD + lane * 4) = o;
  } else {
    int t = bid - 4096;
    const float* src; unsigned short* dst; int K, N;
    if (t < 64) { src = w1; dst = w1bT; K = 256; N = 1024; }
    else        { src = w2; dst = w2bT; K = 1024; N = 256; t -= 64; }
    int nt = N >> 6;
    int kt = t / nt, ntb = t % nt;
    int k0 = kt * 64, n0 = ntb * 64;
    int tt = threadIdx.x;
    int r = tt >> 2, c4 = (tt & 3) * 16;
    const float* s = src + (size_t)(k0 + r) * N + n0 + c4;
#pragma unroll
    for (int j = 0; j < 16; ++j) tile[r][c4 + j] = tobf(s[j]);
    __syncthreads();
    union { unsigned short us[16]; uint4 u[2]; } tmp;
    int nr = tt >> 2, ks = (tt & 3) * 16;
#pragma unroll
    for (int j = 0; j < 16; ++j) tmp.us[j] = tile[ks + j][nr];
    unsigned short* d = dst + (size_t)(n0 + nr) * K + k0 + ks;
    *(uint4*)d = tmp.u[0];
    *(uint4*)(d + 8) = tmp.u[1];
  }
}

// ------ tqk: transpose (1024 blocks) | symmetric qk (1088 blocks) -----------
// Both read only hb; independent outputs; similar LDS footprint (<=17.4KB).
__global__ __launch_bounds__(256) void tqk_kernel(
    const unsigned short* __restrict__ hb,
    unsigned short* __restrict__ hbT,
    unsigned short* __restrict__ S) {
  __shared__ unsigned short smem[17408];
  int bid = blockIdx.x;
  if (bid < 1024) {
    unsigned short (*tile)[72] = (unsigned short (*)[72])smem;
    int b = bid >> 7;
    int rest = bid & 127;
    int st = rest >> 2, dt = rest & 3;
    int s0 = st * 64, d0 = dt * 64;
    int t = threadIdx.x;
    int r = t >> 2, cs = (t & 3) * 16;
    const unsigned short* src = hb + ((size_t)b * SS + s0 + r) * DD + d0 + cs;
    *(uint4*)&tile[r][cs] = *(const uint4*)src;
    *(uint4*)&tile[r][cs + 8] = *(const uint4*)(src + 8);
    __syncthreads();
    union { unsigned short us[16]; uint4 u[2]; } tmp;
    int dr = t >> 2, sseg = (t & 3) * 16;
#pragma unroll
    for (int j = 0; j < 16; ++j) tmp.us[j] = tile[sseg + j][dr];
    unsigned short* dst = hbT + ((size_t)b * DD + d0 + dr) * SS + s0 + sseg;
    *(uint4*)dst = tmp.u[0];
    *(uint4*)(dst + 8) = tmp.u[1];
  } else {
    int t = bid - 1024;
    int b = t & 7;
    int tri = t >> 3;
    int mb = 0, rem = tri;
    while (rem >= 16 - mb) { rem -= 16 - mb; ++mb; }
    int nb = mb + rem;
    const unsigned short* A = hb + (size_t)(b * SS + mb * 128) * DD;
    const unsigned short* Bt = hb + (size_t)(b * SS + nb * 128) * DD;
    f32x4 acc[4][4];
    gemm128_tile<8>(A, DD, Bt, DD, smem, acc);
    int tid = threadIdx.x;
    int w = tid >> 6, lane = tid & 63;
    int lr = lane & 15, lg = lane >> 4;
    int wm = w >> 1, wn = w & 1;
    unsigned short* Sb = S + (size_t)b * SS * SS;
#pragma unroll
    for (int i = 0; i < 4; ++i)
#pragma unroll
      for (int j = 0; j < 4; ++j)
#pragma unroll
        for (int r = 0; r < 4; ++r) {
          int m = mb * 128 + wm * 64 + i * 16 + lg * 4 + r;
          int n = nb * 128 + wn * 64 + j * 16 + lr;
          Sb[(size_t)m * SS + n] = tobf(acc[i][j][r] * 0.0625f);
        }
    if (mb != nb) {
#pragma unroll
      for (int i = 0; i < 4; ++i)
#pragma unroll
        for (int j = 0; j < 4; ++j) {
          int col = wn * 64 + j * 16 + lr;
#pragma unroll
          for (int r = 0; r < 4; ++r) {
            int row = wm * 64 + i * 16 + lg * 4 + r;
            smem[col * LDSW + row] = tobf(acc[i][j][r] * 0.0625f);
          }
        }
      __syncthreads();
      int row2 = tid >> 1, half = (tid & 1) * 64;
      const unsigned short* s = smem + row2 * LDSW + half;
      unsigned short* d = Sb + (size_t)(nb * 128 + row2) * SS + mb * 128 + half;
      uint4 vv[8];
#pragma unroll
      for (int k = 0; k < 8; ++k) vv[k] = *(const uint4*)(s + k * 8);
#pragma unroll
      for (int k = 0; k < 8; ++k) *(uint4*)(d + k * 8) = vv[k];
    }
  }
}

// ---------------- fused row pass: P = softmax(S + softmax(mask(r_mat))) -----
__global__ __launch_bounds__(256) void smfuse_kernel(
    const float* __restrict__ r_mat,
    const float* __restrict__ attn,
    const float* __restrict__ pad,
    unsigned short* __restrict__ S) {
  int row = blockIdx.x * 4 + (threadIdx.x >> 6);
  int lane = threadIdx.x & 63;
  int b = row >> 11, q = row & 2047;
  const float* rrow = r_mat + (size_t)row * SS;
  const float* arow = attn + (size_t)q * SS;
  const float* prow = pad + (size_t)b * SS;
  unsigned short* srow = S + (size_t)row * SS;

  float rm[32];
  float mx = -__builtin_inff();
#pragma unroll
  for (int i = 0; i < 8; ++i) {
    int c = i * 256 + lane * 4;
    float4 rv = *(const float4*)(rrow + c);
    float4 av = *(const float4*)(arow + c);
    float4 pv = *(const float4*)(prow + c);
    float v0 = (pv.x == 0.f || av.x == 0.f) ? NEGV : rv.x;
    float v1 = (pv.y == 0.f || av.y == 0.f) ? NEGV : rv.y;
    float v2 = (pv.z == 0.f || av.z == 0.f) ? NEGV : rv.z;
    float v3 = (pv.w == 0.f || av.w == 0.f) ? NEGV : rv.w;
    rm[i * 4 + 0] = v0; rm[i * 4 + 1] = v1; rm[i * 4 + 2] = v2; rm[i * 4 + 3] = v3;
    mx = fmaxf(mx, fmaxf(fmaxf(v0, v1), fmaxf(v2, v3)));
  }
#pragma unroll
  for (int m = 1; m < 64; m <<= 1) mx = fmaxf(mx, __shfl_xor(mx, m));
  float sum = 0.f;
#pragma unroll
  for (int j = 0; j < 32; ++j) { rm[j] = __expf(rm[j] - mx); sum += rm[j]; }
#pragma unroll
  for (int m = 1; m < 64; m <<= 1) sum += __shfl_xor(sum, m);
  float inv = 1.f / sum;

  float sc[32];
  float mx2 = -__builtin_inff();
#pragma unroll
  for (int i = 0; i < 8; ++i) {
    int c = i * 256 + lane * 4;
    ushort4 sv = *(const ushort4*)(srow + c);
    float s0 = frombf(sv.x) + rm[i * 4 + 0] * inv;
    float s1 = frombf(sv.y) + rm[i * 4 + 1] * inv;
    float s2 = frombf(sv.z) + rm[i * 4 + 2] * inv;
    float s3 = frombf(sv.w) + rm[i * 4 + 3] * inv;
    sc[i * 4 + 0] = s0; sc[i * 4 + 1] = s1; sc[i * 4 + 2] = s2; sc[i * 4 + 3] = s3;
    mx2 = fmaxf(mx2, fmaxf(fmaxf(s0, s1), fmaxf(s2, s3)));
  }
#pragma unroll
  for (int m = 1; m < 64; m <<= 1) mx2 = fmaxf(mx2, __shfl_xor(mx2, m));
  float sum2 = 0.f;
#pragma unroll
  for (int j = 0; j < 32; ++j) { sc[j] = __expf(sc[j] - mx2); sum2 += sc[j]; }
#pragma unroll
  for (int m = 1; m < 64; m <<= 1) sum2 += __shfl_xor(sum2, m);
  float inv2 = 1.f / sum2;
#pragma unroll
  for (int i = 0; i < 8; ++i) {
    int c = i * 256 + lane * 4;
    ushort4 o;
    o.x = tobf(sc[i * 4 + 0] * inv2);
    o.y = tobf(sc[i * 4 + 1] * inv2);
    o.z = tobf(sc[i * 4 + 2] * inv2);
    o.w = tobf(sc[i * 4 + 3] * inv2);
    *(ushort4*)(srow + c) = o;
  }
}

// ---- PV split-K x4, BN=256 8-wave core, direct stores (R10) ----------------
__global__ __launch_bounds__(512) void pv_kernel(
    const unsigned short* __restrict__ P,
    const unsigned short* __restrict__ hbT,
    unsigned short* __restrict__ pvp) {
  __shared__ unsigned short smem[24576];
  int bid = blockIdx.x;
  int b = bid & 7;
  int rest = bid >> 3;
  int ks = rest & 3, mb = rest >> 2;
  const unsigned short* A = P + (size_t)(b * SS + mb * 128) * SS + ks * 512;
  const unsigned short* Bt = hbT + (size_t)(b * DD) * SS + ks * 512;
  f32x4 acc[4][4];
  gemm256_acc<16>(A, SS, Bt, SS, smem, acc);
  int w = threadIdx.x >> 6, lane = threadIdx.x & 63;
  int lr = lane & 15, lg = lane >> 4;
  int wm = w >> 2, wn = w & 3;
  unsigned short* O = pvp + ((size_t)(ks << 14) + (b << 11) + mb * 128) * DD;
#pragma unroll
  for (int i = 0; i < 4; ++i)
#pragma unroll
    for (int j = 0; j < 4; ++j)
#pragma unroll
      for (int r = 0; r < 4; ++r) {
        int m = wm * 64 + i * 16 + lg * 4 + r;
        int n = wn * 64 + j * 16 + lr;
        O[(size_t)m * DD + n] = tobf(acc[i][j][r]);
      }
}

// ---------------- pv reduce + residual + fused LN2 --------------------------
__global__ __launch_bounds__(256) void pvreduce_kernel(
    const unsigned short* __restrict__ pvp,
    const float* __restrict__ x,
    const float* __restrict__ ln2w,
    const float* __restrict__ ln2b,
    float* __restrict__ out,
    unsigned short* __restrict__ h2b) {
  int r = blockIdx.x * 4 + (threadIdx.x >> 6);
  int lane = threadIdx.x & 63;
  int c = lane * 4;
  float o[4] = {0.f, 0.f, 0.f, 0.f};
#pragma unroll
  for (int ks = 0; ks < 4; ++ks) {
    ushort4 pk = *(const ushort4*)(pvp + ((size_t)(ks << 14) + r) * DD + c);
    o[0] += frombf(pk.x); o[1] += frombf(pk.y);
    o[2] += frombf(pk.z); o[3] += frombf(pk.w);
  }
  float4 xv = *(const float4*)(x + (size_t)r * DD + c);
  float val[4] = {o[0] + xv.x, o[1] + xv.y, o[2] + xv.z, o[3] + xv.w};
  float4 ov = {val[0], val[1], val[2], val[3]};
  *(float4*)(out + (size_t)r * DD + c) = ov;
  float s = val[0] + val[1] + val[2] + val[3];
  float s2 = val[0] * val[0] + val[1] * val[1] + val[2] * val[2] + val[3] * val[3];
#pragma unroll
  for (int m = 1; m < 64; m <<= 1) { s += __shfl_xor(s, m); s2 += __shfl_xor(s2, m); }
  float mu = s * (1.f / DD);
  float var = s2 * (1.f / DD) - mu * mu;
  float rsv = rsqrtf(var + 1e-5f);
  float4 wv = *(const float4*)(ln2w + c);
  float4 bv = *(const float4*)(ln2b + c);
  ushort4 h;
  h.x = tobf((val[0] - mu) * rsv * wv.x + bv.x);
  h.y = tobf((val[1] - mu) * rsv * wv.y + bv.y);
  h.z = tobf((val[2] - mu) * rsv * wv.z + bv.z);
  h.w = tobf((val[3] - mu) * rsv * wv.w + bv.w);
  *(ushort4*)(h2b + (size_t)r * DD + c) = h;
}

// ---- FFN1: relu(h2b @ w1 + b1), BN=256 8-wave core, direct stores ----------
__global__ __launch_bounds__(512) void ffn1_kernel(
    const unsigned short* __restrict__ A0,
    const unsigned short* __restrict__ Bt0,
    const float* __restrict__ bias,
    unsigned short* __restrict__ Out) {
  __shared__ unsigned short smem[24576];
  int bid = blockIdx.x;
  int nb = bid & 3, mb = bid >> 2;
  const unsigned short* A = A0 + (size_t)(mb * 128) * 256;
  const unsigned short* Bt = Bt0 + (size_t)(nb * 256) * 256;
  f32x4 acc[4][4];
  gemm256_acc<8>(A, 256, Bt, 256, smem, acc);
  int w = threadIdx.x >> 6, lane = threadIdx.x & 63;
  int lr = lane & 15, lg = lane >> 4;
  int wm = w >> 2, wn = w & 3;
#pragma unroll
  for (int i = 0; i < 4; ++i)
#pragma unroll
    for (int j = 0; j < 4; ++j)
#pragma unroll
      for (int r = 0; r < 4; ++r) {
        int m = mb * 128 + wm * 64 + i * 16 + lg * 4 + r;
        int n = nb * 256 + wn * 64 + j * 16 + lr;
        float v = fmaxf(acc[i][j][r] + bias[n], 0.f);
        Out[(size_t)m * 1024 + n] = tobf(v);
      }
}

// ---- FFN2 split-K x4, BN=256 8-wave core, direct stores --------------------
__global__ __launch_bounds__(512) void ffn2_kernel(
    const unsigned short* __restrict__ A0,
    const unsigned short* __restrict__ Bt0,
    unsigned short* __restrict__ f2p) {
  __shared__ unsigned short smem[24576];
  int bid = blockIdx.x;
  int ks = bid & 3, mb = bid >> 2;
  const unsigned short* A = A0 + (size_t)(mb * 128) * 1024 + ks * 256;
  const unsigned short* Bt = Bt0 + ks * 256;
  f32x4 acc[4][4];
  gemm256_acc<8>(A, 1024, Bt, 1024, smem, acc);
  int w = threadIdx.x >> 6, lane = threadIdx.x & 63;
  int lr = lane & 15, lg = lane >> 4;
  int wm = w >> 2, wn = w & 3;
  unsigned short* O = f2p + ((size_t)(ks << 14) + mb * 128) * DD;
#pragma unroll
  for (int i = 0; i < 4; ++i)
#pragma unroll
    for (int j = 0; j < 4; ++j)
#pragma unroll
      for (int r = 0; r < 4; ++r) {
        int m = wm * 64 + i * 16 + lg * 4 + r;
        int n = wn * 64 + j * 16 + lr;
        O[(size_t)m * DD + n] = tobf(acc[i][j][r]);
      }
}

// ---------------- ffn2 reduce + bias + residual (out += ffn) ----------------
__global__ __launch_bounds__(256) void f2reduce_kernel(
    const unsigned short* __restrict__ f2p,
    const float* __restrict__ bias,
    float* __restrict__ out) {
  int r = blockIdx.x * 4 + (threadIdx.x >> 6);
  int lane = threadIdx.x & 63;
  int c = lane * 4;
  float o[4] = {0.f, 0.f, 0.f, 0.f};
#pragma unroll
  for (int ks = 0; ks < 4; ++ks) {
    ushort4 pk = *(const ushort4*)(f2p + ((size_t)(ks << 14) + r) * DD + c);
    o[0] += frombf(pk.x); o[1] += frombf(pk.y);
    o[2] += frombf(pk.z); o[3] += frombf(pk.w);
  }
  float4 bv = *(const float4*)(bias + c);
  float* orow = out + (size_t)r * DD + c;
  float4 cur = *(const float4*)orow;
  float4 res = {cur.x + o[0] + bv.x, cur.y + o[1] + bv.y,
                cur.z + o[2] + bv.z, cur.w + o[3] + bv.w};
  *(float4*)orow = res;
}

extern "C" void kernel_launch(void* const* d_in, const int* in_sizes, int n_in,
                              void* d_out, int out_size, void* d_ws, size_t ws_size,
                              hipStream_t stream) {
  const float* x     = (const float*)d_in[0];
  const float* r_mat = (const float*)d_in[1];
  const float* attn  = (const float*)d_in[2];
  const float* pad   = (const float*)d_in[3];
  const float* ln1w  = (const float*)d_in[4];
  const float* ln1b  = (const float*)d_in[5];
  const float* ln2w  = (const float*)d_in[6];
  const float* ln2b  = (const float*)d_in[7];
  const float* w1    = (const float*)d_in[8];
  const float* b1    = (const float*)d_in[9];
  const float* w2    = (const float*)d_in[10];
  const float* b2    = (const float*)d_in[11];
  float* out = (float*)d_out;

  uint8_t* ws = (uint8_t*)d_ws;
  unsigned short* hb   = (unsigned short*)(ws + 0);           // 8 MB
  unsigned short* hbT  = (unsigned short*)(ws + 8388608);     // 8 MB
  unsigned short* h2b  = (unsigned short*)(ws + 16777216);    // 8 MB
  unsigned short* w1bT = (unsigned short*)(ws + 25165824);    // 0.5 MB
  unsigned short* w2bT = (unsigned short*)(ws + 25690112);    // 0.5 MB
  unsigned short* S    = (unsigned short*)(ws + 33554432);    // 67 MB bf16 [B,S,S]
  unsigned short* pvp  = (unsigned short*)(ws + 100663296);   // 33.5 MB bf16 [4][B*S][D]
  unsigned short* t    = S;                                   // ffn1 out aliases S
  unsigned short* f2p  = pvp;                                 // ffn2 partials alias pvp

  hipLaunchKernelGGL(lnw_kernel, dim3(4224), dim3(256), 0, stream,
                     x, ln1w, ln1b, hb, w1, w1bT, w2, w2bT);
  hipLaunchKernelGGL(tqk_kernel, dim3(2112), dim3(256), 0, stream, hb, hbT, S);
  hipLaunchKernelGGL(smfuse_kernel, dim3(4096), dim3(256), 0, stream, r_mat, attn, pad, S);
  hipLaunchKernelGGL(pv_kernel, dim3(512), dim3(512), 0, stream, S, hbT, pvp);
  hipLaunchKernelGGL(pvreduce_kernel, dim3(4096), dim3(256), 0, stream,
                     pvp, x, ln2w, ln2b, out, h2b);
  hipLaunchKernelGGL(ffn1_kernel, dim3(512), dim3(512), 0, stream, h2b, w1bT, b1, t);
  hipLaunchKernelGGL(ffn2_kernel, dim3(512), dim3(512), 0, stream, t, w2bT, f2p);
  hipLaunchKernelGGL(f2reduce_kernel, dim3(4096), dim3(256), 0, stream, f2p, b2, out);
}